// Round 4
// baseline (1401.870 us; speedup 1.0000x reference)
//
#include <hip/hip_runtime.h>

#define NN 100000
#define EE 1600000
#define HD 128
#define GG 64
#define NB 391          // ceil(NN/256)
#define BNEPS 1e-5f

// ---------------- degree histogram + dinv ----------------
__global__ void k_hist(const int* __restrict__ ei, int* __restrict__ cnt){
  int e = blockIdx.x*256 + threadIdx.x;
  if (e < EE) atomicAdd(&cnt[ei[EE + e]], 1);
}

__global__ void k_dinv(const int* __restrict__ cnt, float* __restrict__ dinv){
  int n = blockIdx.x*256 + threadIdx.x;
  if (n < NN) dinv[n] = rsqrtf(1.0f + (float)cnt[n]);
}

// ---------------- exclusive scan of degree counts ----------------
__global__ void k_scanA(const int* __restrict__ cnt, int* __restrict__ offs,
                        int* __restrict__ bsum){
  __shared__ int s[256];
  int tid = threadIdx.x;
  int n = blockIdx.x*256 + tid;
  int v = (n < NN) ? cnt[n] : 0;
  s[tid] = v; __syncthreads();
  for (int d = 1; d < 256; d <<= 1){
    int t = (tid >= d) ? s[tid-d] : 0;
    __syncthreads();
    s[tid] += t;
    __syncthreads();
  }
  if (n < NN) offs[n] = s[tid] - v;          // block-local exclusive
  if (tid == 255) bsum[blockIdx.x] = s[255]; // block total
}

__global__ void k_scanB(int* __restrict__ bsum){
  __shared__ int s[512];
  int tid = threadIdx.x;
  int v = (tid < NB) ? bsum[tid] : 0;
  s[tid] = v; __syncthreads();
  for (int d = 1; d < 512; d <<= 1){
    int t = (tid >= d) ? s[tid-d] : 0;
    __syncthreads();
    s[tid] += t;
    __syncthreads();
  }
  if (tid < NB) bsum[tid] = s[tid] - v;      // exclusive block bases
}

__global__ void k_scanC(int* __restrict__ offs, const int* __restrict__ bsum){
  int n = blockIdx.x*256 + threadIdx.x;
  if (n < NN) offs[n] += bsum[blockIdx.x];
  if (n == 0) offs[NN] = EE;
}

// ---------------- CSR scatter: (src, dinv[src]) per edge ----------------
__global__ void k_scatter(const int* __restrict__ ei, const int* __restrict__ offs,
                          int* __restrict__ cursor, const float* __restrict__ dinv,
                          int2* __restrict__ csr){
  int e = blockIdx.x*256 + threadIdx.x;
  if (e >= EE) return;
  int s = ei[e], d = ei[EE + e];
  int pos = offs[d] + atomicAdd(&cursor[d], 1);
  csr[pos] = make_int2(s, __float_as_int(dinv[s]));
}

// ---------------- aggregation: agg[n] = dinv[n]*(sum h[s]*dinv[s] + h[n]*dinv[n]) + b
//    MLP-restructured: 2 half-waves (32 lanes x float4) on alternating edges,
//    unroll-by-2 + depth-2 index prefetch -> 4 gathers in flight per wave.
//    Fused BN-stat partials (sum, sumsq per channel). ----------------
__global__ void __launch_bounds__(256)
k_agg(const float* __restrict__ h, const int2* __restrict__ csr,
      const int* __restrict__ offs, const float* __restrict__ dinv,
      const float* __restrict__ bias, float* __restrict__ agg,
      float* __restrict__ bns){
  const int wib  = threadIdx.x >> 6;   // wave in block (0..3)
  const int lane = threadIdx.x & 63;
  const int half = lane >> 5;          // 0/1: which edge-parity stream
  const int l32  = lane & 31;
  const int c0   = l32*4;              // 4 channels per lane
  const int gw = blockIdx.x*4 + wib;   // wave per node
  const int nw = gridDim.x*4;
  const float4 b4 = *(const float4*)&bias[c0];
  float4 bsum = make_float4(0.f,0.f,0.f,0.f);
  float4 bsq  = make_float4(0.f,0.f,0.f,0.f);
  const int2 zz = make_int2(0, 0);     // sentinel: src=0, weight=+0.0f

  for (int n = gw; n < NN; n += nw){
    const float dn = dinv[n];
    const int b0 = offs[n], deg = offs[n+1] - b0;
    float4 a = make_float4(0.f,0.f,0.f,0.f);
    if (half == 0){                    // self-loop term (dinv[n] factored outside)
      const float4 hv = *(const float4*)&h[(size_t)n*HD + c0];
      a.x = hv.x*dn; a.y = hv.y*dn; a.z = hv.z*dn; a.w = hv.w*dn;
    }
    // this half-wave handles e = b0+half, b0+half+2, ... : cnt entries
    const int cnt = (deg - half + 1) >> 1;
    const int2* cp = csr + b0 + half;
    int2 p0 = (cnt > 0) ? cp[0] : zz;
    int2 p1 = (cnt > 1) ? cp[2] : zz;
    int i = 0;
    for (; i + 1 < cnt; i += 2){
      // issue both gathers before consuming either -> 2 in flight per stream
      const float4 ha = *(const float4*)&h[(size_t)p0.x*HD + c0];
      const float4 hb = *(const float4*)&h[(size_t)p1.x*HD + c0];
      const float wa = __int_as_float(p0.y);
      const float wb = __int_as_float(p1.y);
      const int2 pn0 = (i+2 < cnt) ? cp[2*(i+2)] : zz;
      const int2 pn1 = (i+3 < cnt) ? cp[2*(i+3)] : zz;
      a.x = fmaf(ha.x, wa, a.x); a.y = fmaf(ha.y, wa, a.y);
      a.z = fmaf(ha.z, wa, a.z); a.w = fmaf(ha.w, wa, a.w);
      a.x = fmaf(hb.x, wb, a.x); a.y = fmaf(hb.y, wb, a.y);
      a.z = fmaf(hb.z, wb, a.z); a.w = fmaf(hb.w, wb, a.w);
      p0 = pn0; p1 = pn1;
    }
    if (i < cnt){
      const float4 ha = *(const float4*)&h[(size_t)p0.x*HD + c0];
      const float wa = __int_as_float(p0.y);
      a.x = fmaf(ha.x, wa, a.x); a.y = fmaf(ha.y, wa, a.y);
      a.z = fmaf(ha.z, wa, a.z); a.w = fmaf(ha.w, wa, a.w);
    }
    // combine the two half-wave partials into lanes 0..31
    a.x += __shfl(a.x, l32 + 32, 64);
    a.y += __shfl(a.y, l32 + 32, 64);
    a.z += __shfl(a.z, l32 + 32, 64);
    a.w += __shfl(a.w, l32 + 32, 64);
    if (half == 0){
      float4 o;
      o.x = fmaf(a.x, dn, b4.x); o.y = fmaf(a.y, dn, b4.y);
      o.z = fmaf(a.z, dn, b4.z); o.w = fmaf(a.w, dn, b4.w);
      *(float4*)&agg[(size_t)n*HD + c0] = o;
      bsum.x += o.x; bsum.y += o.y; bsum.z += o.z; bsum.w += o.w;
      bsq.x  = fmaf(o.x,o.x,bsq.x); bsq.y = fmaf(o.y,o.y,bsq.y);
      bsq.z  = fmaf(o.z,o.z,bsq.z); bsq.w = fmaf(o.w,o.w,bsq.w);
    }
  }
  __shared__ float red[4][32][9];      // pad 9: avoid 4-way bank conflict
  if (half == 0){
    red[wib][l32][0]=bsum.x; red[wib][l32][1]=bsum.y;
    red[wib][l32][2]=bsum.z; red[wib][l32][3]=bsum.w;
    red[wib][l32][4]=bsq.x;  red[wib][l32][5]=bsq.y;
    red[wib][l32][6]=bsq.z;  red[wib][l32][7]=bsq.w;
  }
  __syncthreads();
  if (wib == 0 && half == 0){
    float r[8];
    #pragma unroll
    for (int j=0;j<8;j++){
      r[j] = red[0][l32][j] + red[1][l32][j] + red[2][l32][j] + red[3][l32][j];
    }
    atomicAdd(&bns[c0  ],    r[0]);
    atomicAdd(&bns[c0+1],    r[1]);
    atomicAdd(&bns[c0+2],    r[2]);
    atomicAdd(&bns[c0+3],    r[3]);
    atomicAdd(&bns[HD+c0  ], r[4]);
    atomicAdd(&bns[HD+c0+1], r[5]);
    atomicAdd(&bns[HD+c0+2], r[6]);
    atomicAdd(&bns[HD+c0+3], r[7]);
  }
}

// ---------------- BN finalize: scale/shift per channel ----------------
__global__ void k_bnfin(const float* __restrict__ bns, const float* __restrict__ g,
                        const float* __restrict__ be, float* __restrict__ scale,
                        float* __restrict__ shift){
  int c = threadIdx.x;
  float m = bns[c] * (1.0f/NN);
  float v = bns[HD+c] * (1.0f/NN) - m*m;
  float sc = g[c] * rsqrtf(v + BNEPS);
  scale[c] = sc;
  shift[c] = be[c] - m*sc;
}

// ---------------- node-row GEMM: OUT = f(A) @ W  (128x128 W)
// MODE 0: f = identity (layer-1 input x)
// MODE 1: f = relu(bn(A));        also writes f(A) to HOUT (residual save)
// MODE 2: f = relu(bn(A)) + res;  also writes f(A) to HOUT ----------------
template<int MODE>
__global__ void __launch_bounds__(256)
k_rowgemm(const float* __restrict__ A, const float* __restrict__ res,
          const float* __restrict__ W, const float* __restrict__ scale,
          const float* __restrict__ shift,
          float* __restrict__ OUT, float* __restrict__ HOUT){
  __shared__ float Wl[32*128];   // W chunk, rows kk..kk+31
  __shared__ float At[32*68];    // A chunk transposed [k][node], pad 68
  const int tid = threadIdx.x;
  const int n0 = blockIdx.x*64;
  const int tx = tid & 31;       // output-channel group (4 ch)
  const int ty = tid >> 5;       // node group (8 nodes)
  float4 acc[8];
  #pragma unroll
  for (int i=0;i<8;i++) acc[i] = make_float4(0.f,0.f,0.f,0.f);

  for (int kk=0; kk<128; kk+=32){
    #pragma unroll
    for (int p=0;p<4;p++){
      int idx = tid*4 + p*1024;
      *(float4*)&Wl[idx] = *(const float4*)&W[kk*128 + idx];
    }
    #pragma unroll
    for (int p=0;p<2;p++){
      int idx = tid*4 + p*1024;   // 0..2047
      int r = idx >> 5;           // node 0..63
      int c = idx & 31;           // k-col, step 4
      int n = n0 + r;
      float4 v = make_float4(0.f,0.f,0.f,0.f);
      if (n < NN){
        v = *(const float4*)&A[(size_t)n*HD + kk + c];
        if (MODE >= 1){
          const float4 sc = *(const float4*)&scale[kk+c];
          const float4 sh = *(const float4*)&shift[kk+c];
          v.x = fmaxf(fmaf(v.x, sc.x, sh.x), 0.f);
          v.y = fmaxf(fmaf(v.y, sc.y, sh.y), 0.f);
          v.z = fmaxf(fmaf(v.z, sc.z, sh.z), 0.f);
          v.w = fmaxf(fmaf(v.w, sc.w, sh.w), 0.f);
          if (MODE == 2){
            const float4 rv = *(const float4*)&res[(size_t)n*HD + kk + c];
            v.x += rv.x; v.y += rv.y; v.z += rv.z; v.w += rv.w;
          }
          *(float4*)&HOUT[(size_t)n*HD + kk + c] = v;
        }
      }
      At[(c+0)*68 + r] = v.x;
      At[(c+1)*68 + r] = v.y;
      At[(c+2)*68 + r] = v.z;
      At[(c+3)*68 + r] = v.w;
    }
    __syncthreads();
    #pragma unroll 8
    for (int k=0;k<32;k++){
      const float4 b  = *(const float4*)&Wl[k*128 + tx*4];
      const float4 a0 = *(const float4*)&At[k*68 + ty*8];
      const float4 a1 = *(const float4*)&At[k*68 + ty*8 + 4];
      const float av[8] = {a0.x,a0.y,a0.z,a0.w,a1.x,a1.y,a1.z,a1.w};
      #pragma unroll
      for (int i=0;i<8;i++){
        acc[i].x = fmaf(av[i], b.x, acc[i].x);
        acc[i].y = fmaf(av[i], b.y, acc[i].y);
        acc[i].z = fmaf(av[i], b.z, acc[i].z);
        acc[i].w = fmaf(av[i], b.w, acc[i].w);
      }
    }
    __syncthreads();
  }
  #pragma unroll
  for (int i=0;i<8;i++){
    int n = n0 + ty*8 + i;
    if (n < NN) *(float4*)&OUT[(size_t)n*HD + tx*4] = acc[i];
  }
}

// ---------------- layer-3 epilogue + segment pooling (batch is sorted) ----------------
__global__ void __launch_bounds__(128)
k_pool(const float* __restrict__ agg, const float* __restrict__ scale,
       const float* __restrict__ shift, const float* __restrict__ h2,
       const int* __restrict__ batch, float* __restrict__ pool,
       float* __restrict__ pcnt){
  const int t = threadIdx.x;
  const int n0 = blockIdx.x*128;
  const float sc = scale[t], sh = shift[t];
  float racc = 0.f;
  int cur = -1, runlen = 0;
  for (int i=0;i<128;i++){
    int n = n0 + i;
    if (n >= NN) break;
    int g = batch[n];
    float v = fmaxf(fmaf(agg[(size_t)n*HD + t], sc, sh), 0.f) + h2[(size_t)n*HD + t];
    if (g != cur){
      if (cur >= 0){
        atomicAdd(&pool[cur*HD + t], racc);
        if (t == 0) atomicAdd(&pcnt[cur], (float)runlen);
      }
      cur = g; racc = 0.f; runlen = 0;
    }
    racc += v; runlen++;
  }
  if (cur >= 0){
    atomicAdd(&pool[cur*HD + t], racc);
    if (t == 0) atomicAdd(&pcnt[cur], (float)runlen);
  }
}

// ---------------- MLP head: relu([sum,mean] @ Wm1 + bm1) @ Wm2 + bm2 ----------------
__global__ void __launch_bounds__(128)
k_mlp(const float* __restrict__ pool, const float* __restrict__ pcnt,
      const float* __restrict__ Wm1, const float* __restrict__ bm1,
      const float* __restrict__ Wm2, const float* __restrict__ bm2,
      float* __restrict__ out){
  __shared__ float z[2*HD];
  __shared__ float red[HD];
  const int g = blockIdx.x, t = threadIdx.x;
  float s = pool[g*HD + t];
  float c = fmaxf(pcnt[g], 1.0f);
  z[t] = s; z[HD + t] = s / c;
  __syncthreads();
  float acc = bm1[t];
  for (int i=0;i<2*HD;i++) acc = fmaf(z[i], Wm1[i*HD + t], acc);
  acc = fmaxf(acc, 0.f);
  red[t] = acc * Wm2[t];
  __syncthreads();
  for (int off=64; off>0; off>>=1){
    if (t < off) red[t] += red[t+off];
    __syncthreads();
  }
  if (t == 0) out[g] = red[0] + bm2[0];
}

extern "C" void kernel_launch(void* const* d_in, const int* in_sizes, int n_in,
                              void* d_out, int out_size, void* d_ws, size_t ws_size,
                              hipStream_t stream){
  const float* x   = (const float*)d_in[0];
  const int*  ei   = (const int*)d_in[1];
  const int*  batch= (const int*)d_in[2];
  const float* W1  = (const float*)d_in[3];
  const float* b1  = (const float*)d_in[4];
  const float* W2  = (const float*)d_in[5];
  const float* b2  = (const float*)d_in[6];
  const float* W3  = (const float*)d_in[7];
  const float* b3  = (const float*)d_in[8];
  const float* g1  = (const float*)d_in[9];
  const float* be1 = (const float*)d_in[10];
  const float* g2  = (const float*)d_in[11];
  const float* be2 = (const float*)d_in[12];
  const float* g3  = (const float*)d_in[13];
  const float* be3 = (const float*)d_in[14];
  const float* Wm1 = (const float*)d_in[15];
  const float* bm1 = (const float*)d_in[16];
  const float* Wm2 = (const float*)d_in[17];
  const float* bm2 = (const float*)d_in[18];
  float* out = (float*)d_out;
  (void)in_sizes; (void)n_in; (void)out_size; (void)ws_size;

  // ---- workspace bump allocator (zeroed region first) ----
  char* p = (char*)d_ws;
  auto alloc = [&](size_t bytes)->void*{
    void* r = (void*)p;
    p += (bytes + 511) & ~(size_t)511;
    return r;
  };
  int*   deg    = (int*)  alloc(NN*sizeof(int));       // zeroed
  int*   cursor = (int*)  alloc(NN*sizeof(int));       // zeroed
  float* bns    = (float*)alloc(3*2*HD*sizeof(float)); // zeroed
  float* pool   = (float*)alloc(GG*HD*sizeof(float));  // zeroed
  float* pcnt   = (float*)alloc(GG*sizeof(float));     // zeroed
  size_t zbytes = (size_t)(p - (char*)d_ws);
  int*   offs   = (int*)  alloc((NN+1)*sizeof(int));
  int*   bsum   = (int*)  alloc(512*sizeof(int));
  float* dinv   = (float*)alloc(NN*sizeof(float));
  float* scale  = (float*)alloc(3*HD*sizeof(float));
  float* shift  = (float*)alloc(3*HD*sizeof(float));
  int2*  csr    = (int2*) alloc((size_t)EE*sizeof(int2));
  float* hh     = (float*)alloc((size_t)NN*HD*sizeof(float));
  float* agg    = (float*)alloc((size_t)NN*HD*sizeof(float));
  float* hres   = (float*)alloc((size_t)NN*HD*sizeof(float));

  hipMemsetAsync(d_ws, 0, zbytes, stream);

  // ---- CSR build ----
  k_hist   <<<(EE+255)/256, 256, 0, stream>>>(ei, deg);
  k_dinv   <<<NB, 256, 0, stream>>>(deg, dinv);
  k_scanA  <<<NB, 256, 0, stream>>>(deg, offs, bsum);
  k_scanB  <<<1, 512, 0, stream>>>(bsum);
  k_scanC  <<<NB, 256, 0, stream>>>(offs, bsum);
  k_scatter<<<(EE+255)/256, 256, 0, stream>>>(ei, offs, cursor, dinv, csr);

  const int GB = (NN+63)/64;
  // ---- layer 1 ----
  k_rowgemm<0><<<GB, 256, 0, stream>>>(x,   nullptr, W1, nullptr,    nullptr,    hh, nullptr);
  k_agg       <<<2048, 256, 0, stream>>>(hh, csr, offs, dinv, b1, agg, bns);
  k_bnfin     <<<1, 128, 0, stream>>>(bns,        g1, be1, scale,      shift);
  // ---- layer 2 ----
  k_rowgemm<1><<<GB, 256, 0, stream>>>(agg, nullptr, W2, scale,      shift,      hh, hres);
  k_agg       <<<2048, 256, 0, stream>>>(hh, csr, offs, dinv, b2, agg, bns + 2*HD);
  k_bnfin     <<<1, 128, 0, stream>>>(bns + 2*HD, g2, be2, scale+HD,   shift+HD);
  // ---- layer 3 ----
  k_rowgemm<2><<<GB, 256, 0, stream>>>(agg, hres,    W3, scale+HD,   shift+HD,   hh, hres);
  k_agg       <<<2048, 256, 0, stream>>>(hh, csr, offs, dinv, b3, agg, bns + 4*HD);
  k_bnfin     <<<1, 128, 0, stream>>>(bns + 4*HD, g3, be3, scale+2*HD, shift+2*HD);

  // ---- pooling + MLP ----
  k_pool<<<(NN+127)/128, 128, 0, stream>>>(agg, scale+2*HD, shift+2*HD, hres, batch, pool, pcnt);
  k_mlp <<<GG, 128, 0, stream>>>(pool, pcnt, Wm1, bm1, Wm2, bm2, out);
}

// Round 7
// 1136.387 us; speedup vs baseline: 1.2336x; 1.2336x over previous
//
#include <hip/hip_runtime.h>

#define NN 100000
#define EE 1600000
#define HD 128
#define GG 64
#define NB 391          // ceil(NN/256)
#define BNEPS 1e-5f

typedef unsigned int uint_t;
typedef unsigned short ushort_t;

// fp32 -> bf16 round-to-nearest-even
static __device__ __forceinline__ ushort_t f2bf(float f){
  uint_t b = __float_as_uint(f);
  return (ushort_t)((b + 0x7FFFu + ((b >> 16) & 1u)) >> 16);
}
static __device__ __forceinline__ uint_t pack2bf(float a, float b){
  return (uint_t)f2bf(a) | ((uint_t)f2bf(b) << 16);
}
// unpack uint_t (2 packed bf16) -> 2 floats: lo = element c0, hi = element c0+1
static __device__ __forceinline__ float bflo(uint_t u){ return __uint_as_float(u << 16); }
static __device__ __forceinline__ float bfhi(uint_t u){ return __uint_as_float(u & 0xFFFF0000u); }

// ---------------- degree histogram + dinv ----------------
__global__ void k_hist(const int* __restrict__ ei, int* __restrict__ cnt){
  int e = blockIdx.x*256 + threadIdx.x;
  if (e < EE) atomicAdd(&cnt[ei[EE + e]], 1);
}

__global__ void k_dinv(const int* __restrict__ cnt, float* __restrict__ dinv){
  int n = blockIdx.x*256 + threadIdx.x;
  if (n < NN) dinv[n] = rsqrtf(1.0f + (float)cnt[n]);
}

// ---------------- exclusive scan of degree counts ----------------
__global__ void k_scanA(const int* __restrict__ cnt, int* __restrict__ offs,
                        int* __restrict__ bsum){
  __shared__ int s[256];
  int tid = threadIdx.x;
  int n = blockIdx.x*256 + tid;
  int v = (n < NN) ? cnt[n] : 0;
  s[tid] = v; __syncthreads();
  for (int d = 1; d < 256; d <<= 1){
    int t = (tid >= d) ? s[tid-d] : 0;
    __syncthreads();
    s[tid] += t;
    __syncthreads();
  }
  if (n < NN) offs[n] = s[tid] - v;          // block-local exclusive
  if (tid == 255) bsum[blockIdx.x] = s[255]; // block total
}

__global__ void k_scanB(int* __restrict__ bsum){
  __shared__ int s[512];
  int tid = threadIdx.x;
  int v = (tid < NB) ? bsum[tid] : 0;
  s[tid] = v; __syncthreads();
  for (int d = 1; d < 512; d <<= 1){
    int t = (tid >= d) ? s[tid-d] : 0;
    __syncthreads();
    s[tid] += t;
    __syncthreads();
  }
  if (tid < NB) bsum[tid] = s[tid] - v;      // exclusive block bases
}

__global__ void k_scanC(int* __restrict__ offs, const int* __restrict__ bsum){
  int n = blockIdx.x*256 + threadIdx.x;
  if (n < NN) offs[n] += bsum[blockIdx.x];
  if (n == 0) offs[NN] = EE;
}

// ---------------- CSR scatter: (src, dinv[src]) per edge ----------------
__global__ void k_scatter(const int* __restrict__ ei, const int* __restrict__ offs,
                          int* __restrict__ cursor, const float* __restrict__ dinv,
                          int2* __restrict__ csr){
  int e = blockIdx.x*256 + threadIdx.x;
  if (e >= EE) return;
  int s = ei[e], d = ei[EE + e];
  int pos = offs[d] + atomicAdd(&cursor[d], 1);
  csr[pos] = make_int2(s, __float_as_int(dinv[s]));
}

// ---------------- aggregation (bf16 gather): agg[n] = dinv[n]*(sum hb[s]*dinv[s]
//    + hb[n]*dinv[n]) + b.  Baseline loop shape + depth-1 csr prefetch.
//    Fused BN-stat partials (sum, sumsq per channel). ----------------
__global__ void __launch_bounds__(256)
k_agg(const ushort_t* __restrict__ hb, const int2* __restrict__ csr,
      const int* __restrict__ offs, const float* __restrict__ dinv,
      const float* __restrict__ bias, float* __restrict__ agg,
      float* __restrict__ bns){
  const int wib  = threadIdx.x >> 6;   // wave in block (0..3)
  const int lane = threadIdx.x & 63;
  const int gw = blockIdx.x*4 + wib;   // wave per node
  const int nw = gridDim.x*4;
  const int c0 = lane*2;               // 2 channels per lane (1 packed uint)
  const float2 b2 = *(const float2*)&bias[c0];
  float sx=0.f, sy=0.f, qx=0.f, qy=0.f;
  for (int n = gw; n < NN; n += nw){
    const float dn = dinv[n];
    const uint_t hv = *(const uint_t*)&hb[(size_t)n*HD + c0];
    float ax = bflo(hv)*dn, ay = bfhi(hv)*dn;  // self-loop (dinv[n] factored outside)
    const int b0 = offs[n], b1 = offs[n+1];
    if (b0 < b1){
      int2 p = csr[b0];
      for (int e = b0; e < b1; ++e){
        const int2 pn = csr[e+1];            // csr padded +1: safe at e=b1-1
        const float w = __int_as_float(p.y);
        const uint_t u = *(const uint_t*)&hb[(size_t)p.x*HD + c0];
        ax = fmaf(bflo(u), w, ax);
        ay = fmaf(bfhi(u), w, ay);
        p = pn;
      }
    }
    const float ox = fmaf(ax, dn, b2.x);
    const float oy = fmaf(ay, dn, b2.y);
    *(float2*)&agg[(size_t)n*HD + c0] = make_float2(ox, oy);
    sx += ox; sy += oy; qx += ox*ox; qy += oy*oy;
  }
  __shared__ float red[4][64][4];
  red[wib][lane][0]=sx; red[wib][lane][1]=sy; red[wib][lane][2]=qx; red[wib][lane][3]=qy;
  __syncthreads();
  if (wib == 0){
    float a0=0.f,a1=0.f,a2=0.f,a3=0.f;
    #pragma unroll
    for (int w=0; w<4; ++w){
      a0+=red[w][lane][0]; a1+=red[w][lane][1]; a2+=red[w][lane][2]; a3+=red[w][lane][3];
    }
    atomicAdd(&bns[c0  ],    a0);
    atomicAdd(&bns[c0+1],    a1);
    atomicAdd(&bns[HD+c0  ], a2);
    atomicAdd(&bns[HD+c0+1], a3);
  }
}

// ---------------- BN finalize: scale/shift per channel ----------------
__global__ void k_bnfin(const float* __restrict__ bns, const float* __restrict__ g,
                        const float* __restrict__ be, float* __restrict__ scale,
                        float* __restrict__ shift){
  int c = threadIdx.x;
  float m = bns[c] * (1.0f/NN);
  float v = bns[HD+c] * (1.0f/NN) - m*m;
  float sc = g[c] * rsqrtf(v + BNEPS);
  scale[c] = sc;
  shift[c] = be[c] - m*sc;
}

// ---------------- node-row GEMM: HB(bf16) = f(A) @ W  (128x128 W)
// MODE 0: f = identity (layer-1 input x)
// MODE 1: f = relu(bn(A));        also writes f(A) to HOUT fp32 (residual save)
// MODE 2: f = relu(bn(A)) + res;  also writes f(A) to HOUT fp32 ----------------
template<int MODE>
__global__ void __launch_bounds__(256)
k_rowgemm(const float* __restrict__ A, const float* __restrict__ res,
          const float* __restrict__ W, const float* __restrict__ scale,
          const float* __restrict__ shift,
          ushort_t* __restrict__ HB, float* __restrict__ HOUT){
  __shared__ float Wl[32*128];   // W chunk, rows kk..kk+31
  __shared__ float At[32*68];    // A chunk transposed [k][node], pad 68
  const int tid = threadIdx.x;
  const int n0 = blockIdx.x*64;
  const int tx = tid & 31;       // output-channel group (4 ch)
  const int ty = tid >> 5;       // node group (8 nodes)
  float4 acc[8];
  #pragma unroll
  for (int i=0;i<8;i++) acc[i] = make_float4(0.f,0.f,0.f,0.f);

  for (int kk=0; kk<128; kk+=32){
    #pragma unroll
    for (int p=0;p<4;p++){
      int idx = tid*4 + p*1024;
      *(float4*)&Wl[idx] = *(const float4*)&W[kk*128 + idx];
    }
    #pragma unroll
    for (int p=0;p<2;p++){
      int idx = tid*4 + p*1024;   // 0..2047
      int r = idx >> 5;           // node 0..63
      int c = idx & 31;           // k-col, step 4
      int n = n0 + r;
      float4 v = make_float4(0.f,0.f,0.f,0.f);
      if (n < NN){
        v = *(const float4*)&A[(size_t)n*HD + kk + c];
        if (MODE >= 1){
          const float4 sc = *(const float4*)&scale[kk+c];
          const float4 sh = *(const float4*)&shift[kk+c];
          v.x = fmaxf(fmaf(v.x, sc.x, sh.x), 0.f);
          v.y = fmaxf(fmaf(v.y, sc.y, sh.y), 0.f);
          v.z = fmaxf(fmaf(v.z, sc.z, sh.z), 0.f);
          v.w = fmaxf(fmaf(v.w, sc.w, sh.w), 0.f);
          if (MODE == 2){
            const float4 rv = *(const float4*)&res[(size_t)n*HD + kk + c];
            v.x += rv.x; v.y += rv.y; v.z += rv.z; v.w += rv.w;
          }
          *(float4*)&HOUT[(size_t)n*HD + kk + c] = v;
        }
      }
      At[(c+0)*68 + r] = v.x;
      At[(c+1)*68 + r] = v.y;
      At[(c+2)*68 + r] = v.z;
      At[(c+3)*68 + r] = v.w;
    }
    __syncthreads();
    #pragma unroll 8
    for (int k=0;k<32;k++){
      const float4 b  = *(const float4*)&Wl[k*128 + tx*4];
      const float4 a0 = *(const float4*)&At[k*68 + ty*8];
      const float4 a1 = *(const float4*)&At[k*68 + ty*8 + 4];
      const float av[8] = {a0.x,a0.y,a0.z,a0.w,a1.x,a1.y,a1.z,a1.w};
      #pragma unroll
      for (int i=0;i<8;i++){
        acc[i].x = fmaf(av[i], b.x, acc[i].x);
        acc[i].y = fmaf(av[i], b.y, acc[i].y);
        acc[i].z = fmaf(av[i], b.z, acc[i].z);
        acc[i].w = fmaf(av[i], b.w, acc[i].w);
      }
    }
    __syncthreads();
  }
  #pragma unroll
  for (int i=0;i<8;i++){
    int n = n0 + ty*8 + i;
    if (n < NN){
      *(uint2*)&HB[(size_t)n*HD + tx*4] =
        make_uint2(pack2bf(acc[i].x, acc[i].y), pack2bf(acc[i].z, acc[i].w));
    }
  }
}

// ---------------- layer-3 epilogue + segment pooling (batch is sorted) ----------------
__global__ void __launch_bounds__(128)
k_pool(const float* __restrict__ agg, const float* __restrict__ scale,
       const float* __restrict__ shift, const float* __restrict__ h2,
       const int* __restrict__ batch, float* __restrict__ pool,
       float* __restrict__ pcnt){
  const int t = threadIdx.x;
  const int n0 = blockIdx.x*128;
  const float sc = scale[t], sh = shift[t];
  float racc = 0.f;
  int cur = -1, runlen = 0;
  for (int i=0;i<128;i++){
    int n = n0 + i;
    if (n >= NN) break;
    int g = batch[n];
    float v = fmaxf(fmaf(agg[(size_t)n*HD + t], sc, sh), 0.f) + h2[(size_t)n*HD + t];
    if (g != cur){
      if (cur >= 0){
        atomicAdd(&pool[cur*HD + t], racc);
        if (t == 0) atomicAdd(&pcnt[cur], (float)runlen);
      }
      cur = g; racc = 0.f; runlen = 0;
    }
    racc += v; runlen++;
  }
  if (cur >= 0){
    atomicAdd(&pool[cur*HD + t], racc);
    if (t == 0) atomicAdd(&pcnt[cur], (float)runlen);
  }
}

// ---------------- MLP head: relu([sum,mean] @ Wm1 + bm1) @ Wm2 + bm2 ----------------
__global__ void __launch_bounds__(128)
k_mlp(const float* __restrict__ pool, const float* __restrict__ pcnt,
      const float* __restrict__ Wm1, const float* __restrict__ bm1,
      const float* __restrict__ Wm2, const float* __restrict__ bm2,
      float* __restrict__ out){
  __shared__ float z[2*HD];
  __shared__ float red[HD];
  const int g = blockIdx.x, t = threadIdx.x;
  float s = pool[g*HD + t];
  float c = fmaxf(pcnt[g], 1.0f);
  z[t] = s; z[HD + t] = s / c;
  __syncthreads();
  float acc = bm1[t];
  for (int i=0;i<2*HD;i++) acc = fmaf(z[i], Wm1[i*HD + t], acc);
  acc = fmaxf(acc, 0.f);
  red[t] = acc * Wm2[t];
  __syncthreads();
  for (int off=64; off>0; off>>=1){
    if (t < off) red[t] += red[t+off];
    __syncthreads();
  }
  if (t == 0) out[g] = red[0] + bm2[0];
}

extern "C" void kernel_launch(void* const* d_in, const int* in_sizes, int n_in,
                              void* d_out, int out_size, void* d_ws, size_t ws_size,
                              hipStream_t stream){
  const float* x   = (const float*)d_in[0];
  const int*  ei   = (const int*)d_in[1];
  const int*  batch= (const int*)d_in[2];
  const float* W1  = (const float*)d_in[3];
  const float* b1  = (const float*)d_in[4];
  const float* W2  = (const float*)d_in[5];
  const float* b2  = (const float*)d_in[6];
  const float* W3  = (const float*)d_in[7];
  const float* b3  = (const float*)d_in[8];
  const float* g1  = (const float*)d_in[9];
  const float* be1 = (const float*)d_in[10];
  const float* g2  = (const float*)d_in[11];
  const float* be2 = (const float*)d_in[12];
  const float* g3  = (const float*)d_in[13];
  const float* be3 = (const float*)d_in[14];
  const float* Wm1 = (const float*)d_in[15];
  const float* bm1 = (const float*)d_in[16];
  const float* Wm2 = (const float*)d_in[17];
  const float* bm2 = (const float*)d_in[18];
  float* out = (float*)d_out;
  (void)in_sizes; (void)n_in; (void)out_size; (void)ws_size;

  // ---- workspace bump allocator (zeroed region first) ----
  char* p = (char*)d_ws;
  auto alloc = [&](size_t bytes)->void*{
    void* r = (void*)p;
    p += (bytes + 511) & ~(size_t)511;
    return r;
  };
  int*   deg    = (int*)  alloc(NN*sizeof(int));       // zeroed
  int*   cursor = (int*)  alloc(NN*sizeof(int));       // zeroed
  float* bns    = (float*)alloc(3*2*HD*sizeof(float)); // zeroed
  float* pool   = (float*)alloc(GG*HD*sizeof(float));  // zeroed
  float* pcnt   = (float*)alloc(GG*sizeof(float));     // zeroed
  size_t zbytes = (size_t)(p - (char*)d_ws);
  int*   offs   = (int*)  alloc((NN+1)*sizeof(int));
  int*   bsum   = (int*)  alloc(512*sizeof(int));
  float* dinv   = (float*)alloc(NN*sizeof(float));
  float* scale  = (float*)alloc(3*HD*sizeof(float));
  float* shift  = (float*)alloc(3*HD*sizeof(float));
  int2*  csr    = (int2*) alloc(((size_t)EE+1)*sizeof(int2)); // +1: prefetch pad
  ushort_t* hb  = (ushort_t*)alloc((size_t)NN*HD*sizeof(ushort_t)); // bf16 h
  float* agg    = (float*)alloc((size_t)NN*HD*sizeof(float));
  float* hres   = (float*)alloc((size_t)NN*HD*sizeof(float));

  hipMemsetAsync(d_ws, 0, zbytes, stream);

  // ---- CSR build ----
  k_hist   <<<(EE+255)/256, 256, 0, stream>>>(ei, deg);
  k_dinv   <<<NB, 256, 0, stream>>>(deg, dinv);
  k_scanA  <<<NB, 256, 0, stream>>>(deg, offs, bsum);
  k_scanB  <<<1, 512, 0, stream>>>(bsum);
  k_scanC  <<<NB, 256, 0, stream>>>(offs, bsum);
  k_scatter<<<(EE+255)/256, 256, 0, stream>>>(ei, offs, cursor, dinv, csr);

  const int GB = (NN+63)/64;
  // ---- layer 1 ----
  k_rowgemm<0><<<GB, 256, 0, stream>>>(x,   nullptr, W1, nullptr,    nullptr,    hb, nullptr);
  k_agg       <<<2048, 256, 0, stream>>>(hb, csr, offs, dinv, b1, agg, bns);
  k_bnfin     <<<1, 128, 0, stream>>>(bns,        g1, be1, scale,      shift);
  // ---- layer 2 ----
  k_rowgemm<1><<<GB, 256, 0, stream>>>(agg, nullptr, W2, scale,      shift,      hb, hres);
  k_agg       <<<2048, 256, 0, stream>>>(hb, csr, offs, dinv, b2, agg, bns + 2*HD);
  k_bnfin     <<<1, 128, 0, stream>>>(bns + 2*HD, g2, be2, scale+HD,   shift+HD);
  // ---- layer 3 ----
  k_rowgemm<2><<<GB, 256, 0, stream>>>(agg, hres,    W3, scale+HD,   shift+HD,   hb, hres);
  k_agg       <<<2048, 256, 0, stream>>>(hb, csr, offs, dinv, b3, agg, bns + 4*HD);
  k_bnfin     <<<1, 128, 0, stream>>>(bns + 4*HD, g3, be3, scale+2*HD, shift+2*HD);

  // ---- pooling + MLP ----
  k_pool<<<(NN+127)/128, 128, 0, stream>>>(agg, scale+2*HD, shift+2*HD, hres, batch, pool, pcnt);
  k_mlp <<<GG, 128, 0, stream>>>(pool, pcnt, Wm1, bm1, Wm2, bm2, out);
}

// Round 8
// 966.844 us; speedup vs baseline: 1.4499x; 1.1754x over previous
//
#include <hip/hip_runtime.h>

#define NN 100000
#define EE 1600000
#define HD 128
#define GG 64
#define NB 391          // ceil(NN/256)
#define BNEPS 1e-5f

typedef unsigned int uint_t;
typedef unsigned short ushort_t;

// fp32 -> bf16 round-to-nearest-even
static __device__ __forceinline__ ushort_t f2bf(float f){
  uint_t b = __float_as_uint(f);
  return (ushort_t)((b + 0x7FFFu + ((b >> 16) & 1u)) >> 16);
}
static __device__ __forceinline__ uint_t pack2bf(float a, float b){
  return (uint_t)f2bf(a) | ((uint_t)f2bf(b) << 16);
}
// unpack uint_t (2 packed bf16) -> 2 floats: lo = element c0, hi = element c0+1
static __device__ __forceinline__ float bflo(uint_t u){ return __uint_as_float(u << 16); }
static __device__ __forceinline__ float bfhi(uint_t u){ return __uint_as_float(u & 0xFFFF0000u); }

// ---------------- degree histogram + dinv ----------------
__global__ void k_hist(const int* __restrict__ ei, int* __restrict__ cnt){
  int e = blockIdx.x*256 + threadIdx.x;
  if (e < EE) atomicAdd(&cnt[ei[EE + e]], 1);
}

__global__ void k_dinv(const int* __restrict__ cnt, float* __restrict__ dinv){
  int n = blockIdx.x*256 + threadIdx.x;
  if (n < NN) dinv[n] = rsqrtf(1.0f + (float)cnt[n]);
}

// ---------------- exclusive scan of degree counts ----------------
__global__ void k_scanA(const int* __restrict__ cnt, int* __restrict__ offs,
                        int* __restrict__ bsum){
  __shared__ int s[256];
  int tid = threadIdx.x;
  int n = blockIdx.x*256 + tid;
  int v = (n < NN) ? cnt[n] : 0;
  s[tid] = v; __syncthreads();
  for (int d = 1; d < 256; d <<= 1){
    int t = (tid >= d) ? s[tid-d] : 0;
    __syncthreads();
    s[tid] += t;
    __syncthreads();
  }
  if (n < NN) offs[n] = s[tid] - v;          // block-local exclusive
  if (tid == 255) bsum[blockIdx.x] = s[255]; // block total
}

__global__ void k_scanB(int* __restrict__ bsum){
  __shared__ int s[512];
  int tid = threadIdx.x;
  int v = (tid < NB) ? bsum[tid] : 0;
  s[tid] = v; __syncthreads();
  for (int d = 1; d < 512; d <<= 1){
    int t = (tid >= d) ? s[tid-d] : 0;
    __syncthreads();
    s[tid] += t;
    __syncthreads();
  }
  if (tid < NB) bsum[tid] = s[tid] - v;      // exclusive block bases
}

__global__ void k_scanC(int* __restrict__ offs, const int* __restrict__ bsum){
  int n = blockIdx.x*256 + threadIdx.x;
  if (n < NN) offs[n] += bsum[blockIdx.x];
  if (n == 0) offs[NN] = EE;
}

// ---------------- CSR scatter: (src, dinv[src]) per edge ----------------
__global__ void k_scatter(const int* __restrict__ ei, const int* __restrict__ offs,
                          int* __restrict__ cursor, const float* __restrict__ dinv,
                          int2* __restrict__ csr){
  int e = blockIdx.x*256 + threadIdx.x;
  if (e >= EE) return;
  int s = ei[e], d = ei[EE + e];
  int pos = offs[d] + atomicAdd(&cursor[d], 1);
  csr[pos] = make_int2(s, __float_as_int(dinv[s]));
}

// ---------------- aggregation (bf16 gather): agg[n] = dinv[n]*(sum hb[s]*dinv[s]
//    + hb[n]*dinv[n]) + b.
//    4-deep edge pipeline: issue 4 row-gathers before consuming any ->
//    counted vmcnt waits, 4 loads in flight per wave (vs 1 with the old
//    depth-1-prefetch shape whose consume forced vmcnt(0) full drains).
//    Fused BN-stat partials (sum, sumsq per channel). ----------------
__global__ void __launch_bounds__(256)
k_agg(const ushort_t* __restrict__ hb, const int2* __restrict__ csr,
      const int* __restrict__ offs, const float* __restrict__ dinv,
      const float* __restrict__ bias, float* __restrict__ agg,
      float* __restrict__ bns){
  const int wib  = threadIdx.x >> 6;   // wave in block (0..3)
  const int lane = threadIdx.x & 63;
  const int gw = blockIdx.x*4 + wib;   // wave per node
  const int nw = gridDim.x*4;
  const int c0 = lane*2;               // 2 channels per lane (1 packed uint)
  const float2 b2 = *(const float2*)&bias[c0];
  float sx=0.f, sy=0.f, qx=0.f, qy=0.f;
  for (int n = gw; n < NN; n += nw){
    const float dn = dinv[n];
    const uint_t hv = *(const uint_t*)&hb[(size_t)n*HD + c0];
    float ax = bflo(hv)*dn, ay = bfhi(hv)*dn;  // self-loop (dinv[n] factored outside)
    const int b0 = offs[n], b1 = offs[n+1];
    int e = b0;
    for (; e + 4 <= b1; e += 4){
      const int2 p0 = csr[e+0];
      const int2 p1 = csr[e+1];
      const int2 p2 = csr[e+2];
      const int2 p3 = csr[e+3];
      const uint_t u0 = *(const uint_t*)&hb[(size_t)p0.x*HD + c0];
      const uint_t u1 = *(const uint_t*)&hb[(size_t)p1.x*HD + c0];
      const uint_t u2 = *(const uint_t*)&hb[(size_t)p2.x*HD + c0];
      const uint_t u3 = *(const uint_t*)&hb[(size_t)p3.x*HD + c0];
      const float w0 = __int_as_float(p0.y), w1 = __int_as_float(p1.y);
      const float w2 = __int_as_float(p2.y), w3 = __int_as_float(p3.y);
      ax = fmaf(bflo(u0), w0, ax); ay = fmaf(bfhi(u0), w0, ay);
      ax = fmaf(bflo(u1), w1, ax); ay = fmaf(bfhi(u1), w1, ay);
      ax = fmaf(bflo(u2), w2, ax); ay = fmaf(bfhi(u2), w2, ay);
      ax = fmaf(bflo(u3), w3, ax); ay = fmaf(bfhi(u3), w3, ay);
    }
    for (; e < b1; ++e){
      const int2 p = csr[e];
      const float w = __int_as_float(p.y);
      const uint_t u = *(const uint_t*)&hb[(size_t)p.x*HD + c0];
      ax = fmaf(bflo(u), w, ax);
      ay = fmaf(bfhi(u), w, ay);
    }
    const float ox = fmaf(ax, dn, b2.x);
    const float oy = fmaf(ay, dn, b2.y);
    *(float2*)&agg[(size_t)n*HD + c0] = make_float2(ox, oy);
    sx += ox; sy += oy; qx += ox*ox; qy += oy*oy;
  }
  __shared__ float red[4][64][4];
  red[wib][lane][0]=sx; red[wib][lane][1]=sy; red[wib][lane][2]=qx; red[wib][lane][3]=qy;
  __syncthreads();
  if (wib == 0){
    float a0=0.f,a1=0.f,a2=0.f,a3=0.f;
    #pragma unroll
    for (int w=0; w<4; ++w){
      a0+=red[w][lane][0]; a1+=red[w][lane][1]; a2+=red[w][lane][2]; a3+=red[w][lane][3];
    }
    atomicAdd(&bns[c0  ],    a0);
    atomicAdd(&bns[c0+1],    a1);
    atomicAdd(&bns[HD+c0  ], a2);
    atomicAdd(&bns[HD+c0+1], a3);
  }
}

// ---------------- BN finalize: scale/shift per channel ----------------
__global__ void k_bnfin(const float* __restrict__ bns, const float* __restrict__ g,
                        const float* __restrict__ be, float* __restrict__ scale,
                        float* __restrict__ shift){
  int c = threadIdx.x;
  float m = bns[c] * (1.0f/NN);
  float v = bns[HD+c] * (1.0f/NN) - m*m;
  float sc = g[c] * rsqrtf(v + BNEPS);
  scale[c] = sc;
  shift[c] = be[c] - m*sc;
}

// ---------------- node-row GEMM: HB(bf16) = f(A) @ W  (128x128 W)
// MODE 0: f = identity (layer-1 input x)
// MODE 1: f = relu(bn(A));        also writes f(A) to HOUT fp32 (residual save)
// MODE 2: f = relu(bn(A)) + res;  also writes f(A) to HOUT fp32 ----------------
template<int MODE>
__global__ void __launch_bounds__(256)
k_rowgemm(const float* __restrict__ A, const float* __restrict__ res,
          const float* __restrict__ W, const float* __restrict__ scale,
          const float* __restrict__ shift,
          ushort_t* __restrict__ HB, float* __restrict__ HOUT){
  __shared__ float Wl[32*128];   // W chunk, rows kk..kk+31
  __shared__ float At[32*68];    // A chunk transposed [k][node], pad 68
  const int tid = threadIdx.x;
  const int n0 = blockIdx.x*64;
  const int tx = tid & 31;       // output-channel group (4 ch)
  const int ty = tid >> 5;       // node group (8 nodes)
  float4 acc[8];
  #pragma unroll
  for (int i=0;i<8;i++) acc[i] = make_float4(0.f,0.f,0.f,0.f);

  for (int kk=0; kk<128; kk+=32){
    #pragma unroll
    for (int p=0;p<4;p++){
      int idx = tid*4 + p*1024;
      *(float4*)&Wl[idx] = *(const float4*)&W[kk*128 + idx];
    }
    #pragma unroll
    for (int p=0;p<2;p++){
      int idx = tid*4 + p*1024;   // 0..2047
      int r = idx >> 5;           // node 0..63
      int c = idx & 31;           // k-col, step 4
      int n = n0 + r;
      float4 v = make_float4(0.f,0.f,0.f,0.f);
      if (n < NN){
        v = *(const float4*)&A[(size_t)n*HD + kk + c];
        if (MODE >= 1){
          const float4 sc = *(const float4*)&scale[kk+c];
          const float4 sh = *(const float4*)&shift[kk+c];
          v.x = fmaxf(fmaf(v.x, sc.x, sh.x), 0.f);
          v.y = fmaxf(fmaf(v.y, sc.y, sh.y), 0.f);
          v.z = fmaxf(fmaf(v.z, sc.z, sh.z), 0.f);
          v.w = fmaxf(fmaf(v.w, sc.w, sh.w), 0.f);
          if (MODE == 2){
            const float4 rv = *(const float4*)&res[(size_t)n*HD + kk + c];
            v.x += rv.x; v.y += rv.y; v.z += rv.z; v.w += rv.w;
          }
          *(float4*)&HOUT[(size_t)n*HD + kk + c] = v;
        }
      }
      At[(c+0)*68 + r] = v.x;
      At[(c+1)*68 + r] = v.y;
      At[(c+2)*68 + r] = v.z;
      At[(c+3)*68 + r] = v.w;
    }
    __syncthreads();
    #pragma unroll 8
    for (int k=0;k<32;k++){
      const float4 b  = *(const float4*)&Wl[k*128 + tx*4];
      const float4 a0 = *(const float4*)&At[k*68 + ty*8];
      const float4 a1 = *(const float4*)&At[k*68 + ty*8 + 4];
      const float av[8] = {a0.x,a0.y,a0.z,a0.w,a1.x,a1.y,a1.z,a1.w};
      #pragma unroll
      for (int i=0;i<8;i++){
        acc[i].x = fmaf(av[i], b.x, acc[i].x);
        acc[i].y = fmaf(av[i], b.y, acc[i].y);
        acc[i].z = fmaf(av[i], b.z, acc[i].z);
        acc[i].w = fmaf(av[i], b.w, acc[i].w);
      }
    }
    __syncthreads();
  }
  #pragma unroll
  for (int i=0;i<8;i++){
    int n = n0 + ty*8 + i;
    if (n < NN){
      *(uint2*)&HB[(size_t)n*HD + tx*4] =
        make_uint2(pack2bf(acc[i].x, acc[i].y), pack2bf(acc[i].z, acc[i].w));
    }
  }
}

// ---------------- layer-3 epilogue + segment pooling (batch is sorted) ----------------
__global__ void __launch_bounds__(128)
k_pool(const float* __restrict__ agg, const float* __restrict__ scale,
       const float* __restrict__ shift, const float* __restrict__ h2,
       const int* __restrict__ batch, float* __restrict__ pool,
       float* __restrict__ pcnt){
  const int t = threadIdx.x;
  const int n0 = blockIdx.x*128;
  const float sc = scale[t], sh = shift[t];
  float racc = 0.f;
  int cur = -1, runlen = 0;
  for (int i=0;i<128;i++){
    int n = n0 + i;
    if (n >= NN) break;
    int g = batch[n];
    float v = fmaxf(fmaf(agg[(size_t)n*HD + t], sc, sh), 0.f) + h2[(size_t)n*HD + t];
    if (g != cur){
      if (cur >= 0){
        atomicAdd(&pool[cur*HD + t], racc);
        if (t == 0) atomicAdd(&pcnt[cur], (float)runlen);
      }
      cur = g; racc = 0.f; runlen = 0;
    }
    racc += v; runlen++;
  }
  if (cur >= 0){
    atomicAdd(&pool[cur*HD + t], racc);
    if (t == 0) atomicAdd(&pcnt[cur], (float)runlen);
  }
}

// ---------------- MLP head: relu([sum,mean] @ Wm1 + bm1) @ Wm2 + bm2 ----------------
__global__ void __launch_bounds__(128)
k_mlp(const float* __restrict__ pool, const float* __restrict__ pcnt,
      const float* __restrict__ Wm1, const float* __restrict__ bm1,
      const float* __restrict__ Wm2, const float* __restrict__ bm2,
      float* __restrict__ out){
  __shared__ float z[2*HD];
  __shared__ float red[HD];
  const int g = blockIdx.x, t = threadIdx.x;
  float s = pool[g*HD + t];
  float c = fmaxf(pcnt[g], 1.0f);
  z[t] = s; z[HD + t] = s / c;
  __syncthreads();
  float acc = bm1[t];
  for (int i=0;i<2*HD;i++) acc = fmaf(z[i], Wm1[i*HD + t], acc);
  acc = fmaxf(acc, 0.f);
  red[t] = acc * Wm2[t];
  __syncthreads();
  for (int off=64; off>0; off>>=1){
    if (t < off) red[t] += red[t+off];
    __syncthreads();
  }
  if (t == 0) out[g] = red[0] + bm2[0];
}

extern "C" void kernel_launch(void* const* d_in, const int* in_sizes, int n_in,
                              void* d_out, int out_size, void* d_ws, size_t ws_size,
                              hipStream_t stream){
  const float* x   = (const float*)d_in[0];
  const int*  ei   = (const int*)d_in[1];
  const int*  batch= (const int*)d_in[2];
  const float* W1  = (const float*)d_in[3];
  const float* b1  = (const float*)d_in[4];
  const float* W2  = (const float*)d_in[5];
  const float* b2  = (const float*)d_in[6];
  const float* W3  = (const float*)d_in[7];
  const float* b3  = (const float*)d_in[8];
  const float* g1  = (const float*)d_in[9];
  const float* be1 = (const float*)d_in[10];
  const float* g2  = (const float*)d_in[11];
  const float* be2 = (const float*)d_in[12];
  const float* g3  = (const float*)d_in[13];
  const float* be3 = (const float*)d_in[14];
  const float* Wm1 = (const float*)d_in[15];
  const float* bm1 = (const float*)d_in[16];
  const float* Wm2 = (const float*)d_in[17];
  const float* bm2 = (const float*)d_in[18];
  float* out = (float*)d_out;
  (void)in_sizes; (void)n_in; (void)out_size; (void)ws_size;

  // ---- workspace bump allocator (zeroed region first) ----
  char* p = (char*)d_ws;
  auto alloc = [&](size_t bytes)->void*{
    void* r = (void*)p;
    p += (bytes + 511) & ~(size_t)511;
    return r;
  };
  int*   deg    = (int*)  alloc(NN*sizeof(int));       // zeroed
  int*   cursor = (int*)  alloc(NN*sizeof(int));       // zeroed
  float* bns    = (float*)alloc(3*2*HD*sizeof(float)); // zeroed
  float* pool   = (float*)alloc(GG*HD*sizeof(float));  // zeroed
  float* pcnt   = (float*)alloc(GG*sizeof(float));     // zeroed
  size_t zbytes = (size_t)(p - (char*)d_ws);
  int*   offs   = (int*)  alloc((NN+1)*sizeof(int));
  int*   bsum   = (int*)  alloc(512*sizeof(int));
  float* dinv   = (float*)alloc(NN*sizeof(float));
  float* scale  = (float*)alloc(3*HD*sizeof(float));
  float* shift  = (float*)alloc(3*HD*sizeof(float));
  int2*  csr    = (int2*) alloc(((size_t)EE+4)*sizeof(int2)); // +4: pad
  ushort_t* hb  = (ushort_t*)alloc((size_t)NN*HD*sizeof(ushort_t)); // bf16 h
  float* agg    = (float*)alloc((size_t)NN*HD*sizeof(float));
  float* hres   = (float*)alloc((size_t)NN*HD*sizeof(float));

  hipMemsetAsync(d_ws, 0, zbytes, stream);

  // ---- CSR build ----
  k_hist   <<<(EE+255)/256, 256, 0, stream>>>(ei, deg);
  k_dinv   <<<NB, 256, 0, stream>>>(deg, dinv);
  k_scanA  <<<NB, 256, 0, stream>>>(deg, offs, bsum);
  k_scanB  <<<1, 512, 0, stream>>>(bsum);
  k_scanC  <<<NB, 256, 0, stream>>>(offs, bsum);
  k_scatter<<<(EE+255)/256, 256, 0, stream>>>(ei, offs, cursor, dinv, csr);

  const int GB = (NN+63)/64;
  // ---- layer 1 ----
  k_rowgemm<0><<<GB, 256, 0, stream>>>(x,   nullptr, W1, nullptr,    nullptr,    hb, nullptr);
  k_agg       <<<2048, 256, 0, stream>>>(hb, csr, offs, dinv, b1, agg, bns);
  k_bnfin     <<<1, 128, 0, stream>>>(bns,        g1, be1, scale,      shift);
  // ---- layer 2 ----
  k_rowgemm<1><<<GB, 256, 0, stream>>>(agg, nullptr, W2, scale,      shift,      hb, hres);
  k_agg       <<<2048, 256, 0, stream>>>(hb, csr, offs, dinv, b2, agg, bns + 2*HD);
  k_bnfin     <<<1, 128, 0, stream>>>(bns + 2*HD, g2, be2, scale+HD,   shift+HD);
  // ---- layer 3 ----
  k_rowgemm<2><<<GB, 256, 0, stream>>>(agg, hres,    W3, scale+HD,   shift+HD,   hb, hres);
  k_agg       <<<2048, 256, 0, stream>>>(hb, csr, offs, dinv, b3, agg, bns + 4*HD);
  k_bnfin     <<<1, 128, 0, stream>>>(bns + 4*HD, g3, be3, scale+2*HD, shift+2*HD);

  // ---- pooling + MLP ----
  k_pool<<<(NN+127)/128, 128, 0, stream>>>(agg, scale+2*HD, shift+2*HD, hres, batch, pool, pcnt);
  k_mlp <<<GG, 128, 0, stream>>>(pool, pcnt, Wm1, bm1, Wm2, bm2, out);
}

// Round 9
// 951.626 us; speedup vs baseline: 1.4731x; 1.0160x over previous
//
#include <hip/hip_runtime.h>

#define NN 100000
#define EE 1600000
#define HD 128
#define GG 64
#define NB 391          // ceil(NN/256)
#define BNEPS 1e-5f

typedef unsigned int uint_t;
typedef unsigned short ushort_t;

// fp32 -> bf16 round-to-nearest-even
static __device__ __forceinline__ ushort_t f2bf(float f){
  uint_t b = __float_as_uint(f);
  return (ushort_t)((b + 0x7FFFu + ((b >> 16) & 1u)) >> 16);
}
static __device__ __forceinline__ uint_t pack2bf(float a, float b){
  return (uint_t)f2bf(a) | ((uint_t)f2bf(b) << 16);
}
// unpack uint_t (2 packed bf16) -> 2 floats: lo = element c0, hi = element c0+1
static __device__ __forceinline__ float bflo(uint_t u){ return __uint_as_float(u << 16); }
static __device__ __forceinline__ float bfhi(uint_t u){ return __uint_as_float(u & 0xFFFF0000u); }

// ---------------- degree histogram + dinv ----------------
__global__ void k_hist(const int* __restrict__ ei, int* __restrict__ cnt){
  int e = blockIdx.x*256 + threadIdx.x;
  if (e < EE) atomicAdd(&cnt[ei[EE + e]], 1);
}

__global__ void k_dinv(const int* __restrict__ cnt, float* __restrict__ dinv){
  int n = blockIdx.x*256 + threadIdx.x;
  if (n < NN) dinv[n] = rsqrtf(1.0f + (float)cnt[n]);
}

// ---------------- exclusive scan of degree counts ----------------
__global__ void k_scanA(const int* __restrict__ cnt, int* __restrict__ offs,
                        int* __restrict__ bsum){
  __shared__ int s[256];
  int tid = threadIdx.x;
  int n = blockIdx.x*256 + tid;
  int v = (n < NN) ? cnt[n] : 0;
  s[tid] = v; __syncthreads();
  for (int d = 1; d < 256; d <<= 1){
    int t = (tid >= d) ? s[tid-d] : 0;
    __syncthreads();
    s[tid] += t;
    __syncthreads();
  }
  if (n < NN) offs[n] = s[tid] - v;          // block-local exclusive
  if (tid == 255) bsum[blockIdx.x] = s[255]; // block total
}

__global__ void k_scanB(int* __restrict__ bsum){
  __shared__ int s[512];
  int tid = threadIdx.x;
  int v = (tid < NB) ? bsum[tid] : 0;
  s[tid] = v; __syncthreads();
  for (int d = 1; d < 512; d <<= 1){
    int t = (tid >= d) ? s[tid-d] : 0;
    __syncthreads();
    s[tid] += t;
    __syncthreads();
  }
  if (tid < NB) bsum[tid] = s[tid] - v;      // exclusive block bases
}

__global__ void k_scanC(int* __restrict__ offs, const int* __restrict__ bsum){
  int n = blockIdx.x*256 + threadIdx.x;
  if (n < NN) offs[n] += bsum[blockIdx.x];
  if (n == 0) offs[NN] = EE;
}

// ---------------- CSR scatter: (src, dinv[src]) per edge ----------------
__global__ void k_scatter(const int* __restrict__ ei, const int* __restrict__ offs,
                          int* __restrict__ cursor, const float* __restrict__ dinv,
                          int2* __restrict__ csr){
  int e = blockIdx.x*256 + threadIdx.x;
  if (e >= EE) return;
  int s = ei[e], d = ei[EE + e];
  int pos = offs[d] + atomicAdd(&cursor[d], 1);
  csr[pos] = make_int2(s, __float_as_int(dinv[s]));
}

// ---------------- aggregation (bf16 gather): agg[n] = dinv[n]*(sum hb[s]*dinv[s]
//    + hb[n]*dinv[n]) + b.
//    8-deep edge pipeline: issue 8 row-gathers before consuming any ->
//    counted vmcnt waits keep 8 loads in flight per wave. 8->4->1 tail.
//    Fused BN-stat partials (sum, sumsq per channel). ----------------
__global__ void __launch_bounds__(256)
k_agg(const ushort_t* __restrict__ hb, const int2* __restrict__ csr,
      const int* __restrict__ offs, const float* __restrict__ dinv,
      const float* __restrict__ bias, float* __restrict__ agg,
      float* __restrict__ bns){
  const int wib  = threadIdx.x >> 6;   // wave in block (0..3)
  const int lane = threadIdx.x & 63;
  const int gw = blockIdx.x*4 + wib;   // wave per node
  const int nw = gridDim.x*4;
  const int c0 = lane*2;               // 2 channels per lane (1 packed uint)
  const float2 b2 = *(const float2*)&bias[c0];
  float sx=0.f, sy=0.f, qx=0.f, qy=0.f;
  for (int n = gw; n < NN; n += nw){
    const float dn = dinv[n];
    const uint_t hv = *(const uint_t*)&hb[(size_t)n*HD + c0];
    float ax = bflo(hv)*dn, ay = bfhi(hv)*dn;  // self-loop (dinv[n] factored outside)
    const int b0 = offs[n], b1 = offs[n+1];
    int e = b0;
    for (; e + 8 <= b1; e += 8){
      const int2 p0 = csr[e+0];
      const int2 p1 = csr[e+1];
      const int2 p2 = csr[e+2];
      const int2 p3 = csr[e+3];
      const int2 p4 = csr[e+4];
      const int2 p5 = csr[e+5];
      const int2 p6 = csr[e+6];
      const int2 p7 = csr[e+7];
      const uint_t u0 = *(const uint_t*)&hb[(size_t)p0.x*HD + c0];
      const uint_t u1 = *(const uint_t*)&hb[(size_t)p1.x*HD + c0];
      const uint_t u2 = *(const uint_t*)&hb[(size_t)p2.x*HD + c0];
      const uint_t u3 = *(const uint_t*)&hb[(size_t)p3.x*HD + c0];
      const uint_t u4 = *(const uint_t*)&hb[(size_t)p4.x*HD + c0];
      const uint_t u5 = *(const uint_t*)&hb[(size_t)p5.x*HD + c0];
      const uint_t u6 = *(const uint_t*)&hb[(size_t)p6.x*HD + c0];
      const uint_t u7 = *(const uint_t*)&hb[(size_t)p7.x*HD + c0];
      const float w0 = __int_as_float(p0.y), w1 = __int_as_float(p1.y);
      const float w2 = __int_as_float(p2.y), w3 = __int_as_float(p3.y);
      const float w4 = __int_as_float(p4.y), w5 = __int_as_float(p5.y);
      const float w6 = __int_as_float(p6.y), w7 = __int_as_float(p7.y);
      ax = fmaf(bflo(u0), w0, ax); ay = fmaf(bfhi(u0), w0, ay);
      ax = fmaf(bflo(u1), w1, ax); ay = fmaf(bfhi(u1), w1, ay);
      ax = fmaf(bflo(u2), w2, ax); ay = fmaf(bfhi(u2), w2, ay);
      ax = fmaf(bflo(u3), w3, ax); ay = fmaf(bfhi(u3), w3, ay);
      ax = fmaf(bflo(u4), w4, ax); ay = fmaf(bfhi(u4), w4, ay);
      ax = fmaf(bflo(u5), w5, ax); ay = fmaf(bfhi(u5), w5, ay);
      ax = fmaf(bflo(u6), w6, ax); ay = fmaf(bfhi(u6), w6, ay);
      ax = fmaf(bflo(u7), w7, ax); ay = fmaf(bfhi(u7), w7, ay);
    }
    for (; e + 4 <= b1; e += 4){
      const int2 p0 = csr[e+0];
      const int2 p1 = csr[e+1];
      const int2 p2 = csr[e+2];
      const int2 p3 = csr[e+3];
      const uint_t u0 = *(const uint_t*)&hb[(size_t)p0.x*HD + c0];
      const uint_t u1 = *(const uint_t*)&hb[(size_t)p1.x*HD + c0];
      const uint_t u2 = *(const uint_t*)&hb[(size_t)p2.x*HD + c0];
      const uint_t u3 = *(const uint_t*)&hb[(size_t)p3.x*HD + c0];
      const float w0 = __int_as_float(p0.y), w1 = __int_as_float(p1.y);
      const float w2 = __int_as_float(p2.y), w3 = __int_as_float(p3.y);
      ax = fmaf(bflo(u0), w0, ax); ay = fmaf(bfhi(u0), w0, ay);
      ax = fmaf(bflo(u1), w1, ax); ay = fmaf(bfhi(u1), w1, ay);
      ax = fmaf(bflo(u2), w2, ax); ay = fmaf(bfhi(u2), w2, ay);
      ax = fmaf(bflo(u3), w3, ax); ay = fmaf(bfhi(u3), w3, ay);
    }
    for (; e < b1; ++e){
      const int2 p = csr[e];
      const float w = __int_as_float(p.y);
      const uint_t u = *(const uint_t*)&hb[(size_t)p.x*HD + c0];
      ax = fmaf(bflo(u), w, ax);
      ay = fmaf(bfhi(u), w, ay);
    }
    const float ox = fmaf(ax, dn, b2.x);
    const float oy = fmaf(ay, dn, b2.y);
    *(float2*)&agg[(size_t)n*HD + c0] = make_float2(ox, oy);
    sx += ox; sy += oy; qx += ox*ox; qy += oy*oy;
  }
  __shared__ float red[4][64][4];
  red[wib][lane][0]=sx; red[wib][lane][1]=sy; red[wib][lane][2]=qx; red[wib][lane][3]=qy;
  __syncthreads();
  if (wib == 0){
    float a0=0.f,a1=0.f,a2=0.f,a3=0.f;
    #pragma unroll
    for (int w=0; w<4; ++w){
      a0+=red[w][lane][0]; a1+=red[w][lane][1]; a2+=red[w][lane][2]; a3+=red[w][lane][3];
    }
    atomicAdd(&bns[c0  ],    a0);
    atomicAdd(&bns[c0+1],    a1);
    atomicAdd(&bns[HD+c0  ], a2);
    atomicAdd(&bns[HD+c0+1], a3);
  }
}

// ---------------- BN finalize: scale/shift per channel ----------------
__global__ void k_bnfin(const float* __restrict__ bns, const float* __restrict__ g,
                        const float* __restrict__ be, float* __restrict__ scale,
                        float* __restrict__ shift){
  int c = threadIdx.x;
  float m = bns[c] * (1.0f/NN);
  float v = bns[HD+c] * (1.0f/NN) - m*m;
  float sc = g[c] * rsqrtf(v + BNEPS);
  scale[c] = sc;
  shift[c] = be[c] - m*sc;
}

// ---------------- node-row GEMM: HB(bf16) = f(A) @ W  (128x128 W)
// MODE 0: f = identity (layer-1 input x)
// MODE 1: f = relu(bn(A));        also writes f(A) to HOUT fp32 (residual save)
// MODE 2: f = relu(bn(A)) + res;  also writes f(A) to HOUT fp32 ----------------
template<int MODE>
__global__ void __launch_bounds__(256)
k_rowgemm(const float* __restrict__ A, const float* __restrict__ res,
          const float* __restrict__ W, const float* __restrict__ scale,
          const float* __restrict__ shift,
          ushort_t* __restrict__ HB, float* __restrict__ HOUT){
  __shared__ float Wl[32*128];   // W chunk, rows kk..kk+31
  __shared__ float At[32*68];    // A chunk transposed [k][node], pad 68
  const int tid = threadIdx.x;
  const int n0 = blockIdx.x*64;
  const int tx = tid & 31;       // output-channel group (4 ch)
  const int ty = tid >> 5;       // node group (8 nodes)
  float4 acc[8];
  #pragma unroll
  for (int i=0;i<8;i++) acc[i] = make_float4(0.f,0.f,0.f,0.f);

  for (int kk=0; kk<128; kk+=32){
    #pragma unroll
    for (int p=0;p<4;p++){
      int idx = tid*4 + p*1024;
      *(float4*)&Wl[idx] = *(const float4*)&W[kk*128 + idx];
    }
    #pragma unroll
    for (int p=0;p<2;p++){
      int idx = tid*4 + p*1024;   // 0..2047
      int r = idx >> 5;           // node 0..63
      int c = idx & 31;           // k-col, step 4
      int n = n0 + r;
      float4 v = make_float4(0.f,0.f,0.f,0.f);
      if (n < NN){
        v = *(const float4*)&A[(size_t)n*HD + kk + c];
        if (MODE >= 1){
          const float4 sc = *(const float4*)&scale[kk+c];
          const float4 sh = *(const float4*)&shift[kk+c];
          v.x = fmaxf(fmaf(v.x, sc.x, sh.x), 0.f);
          v.y = fmaxf(fmaf(v.y, sc.y, sh.y), 0.f);
          v.z = fmaxf(fmaf(v.z, sc.z, sh.z), 0.f);
          v.w = fmaxf(fmaf(v.w, sc.w, sh.w), 0.f);
          if (MODE == 2){
            const float4 rv = *(const float4*)&res[(size_t)n*HD + kk + c];
            v.x += rv.x; v.y += rv.y; v.z += rv.z; v.w += rv.w;
          }
          *(float4*)&HOUT[(size_t)n*HD + kk + c] = v;
        }
      }
      At[(c+0)*68 + r] = v.x;
      At[(c+1)*68 + r] = v.y;
      At[(c+2)*68 + r] = v.z;
      At[(c+3)*68 + r] = v.w;
    }
    __syncthreads();
    #pragma unroll 8
    for (int k=0;k<32;k++){
      const float4 b  = *(const float4*)&Wl[k*128 + tx*4];
      const float4 a0 = *(const float4*)&At[k*68 + ty*8];
      const float4 a1 = *(const float4*)&At[k*68 + ty*8 + 4];
      const float av[8] = {a0.x,a0.y,a0.z,a0.w,a1.x,a1.y,a1.z,a1.w};
      #pragma unroll
      for (int i=0;i<8;i++){
        acc[i].x = fmaf(av[i], b.x, acc[i].x);
        acc[i].y = fmaf(av[i], b.y, acc[i].y);
        acc[i].z = fmaf(av[i], b.z, acc[i].z);
        acc[i].w = fmaf(av[i], b.w, acc[i].w);
      }
    }
    __syncthreads();
  }
  #pragma unroll
  for (int i=0;i<8;i++){
    int n = n0 + ty*8 + i;
    if (n < NN){
      *(uint2*)&HB[(size_t)n*HD + tx*4] =
        make_uint2(pack2bf(acc[i].x, acc[i].y), pack2bf(acc[i].z, acc[i].w));
    }
  }
}

// ---------------- layer-3 epilogue + segment pooling (batch is sorted) ----------------
__global__ void __launch_bounds__(128)
k_pool(const float* __restrict__ agg, const float* __restrict__ scale,
       const float* __restrict__ shift, const float* __restrict__ h2,
       const int* __restrict__ batch, float* __restrict__ pool,
       float* __restrict__ pcnt){
  const int t = threadIdx.x;
  const int n0 = blockIdx.x*128;
  const float sc = scale[t], sh = shift[t];
  float racc = 0.f;
  int cur = -1, runlen = 0;
  for (int i=0;i<128;i++){
    int n = n0 + i;
    if (n >= NN) break;
    int g = batch[n];
    float v = fmaxf(fmaf(agg[(size_t)n*HD + t], sc, sh), 0.f) + h2[(size_t)n*HD + t];
    if (g != cur){
      if (cur >= 0){
        atomicAdd(&pool[cur*HD + t], racc);
        if (t == 0) atomicAdd(&pcnt[cur], (float)runlen);
      }
      cur = g; racc = 0.f; runlen = 0;
    }
    racc += v; runlen++;
  }
  if (cur >= 0){
    atomicAdd(&pool[cur*HD + t], racc);
    if (t == 0) atomicAdd(&pcnt[cur], (float)runlen);
  }
}

// ---------------- MLP head: relu([sum,mean] @ Wm1 + bm1) @ Wm2 + bm2 ----------------
__global__ void __launch_bounds__(128)
k_mlp(const float* __restrict__ pool, const float* __restrict__ pcnt,
      const float* __restrict__ Wm1, const float* __restrict__ bm1,
      const float* __restrict__ Wm2, const float* __restrict__ bm2,
      float* __restrict__ out){
  __shared__ float z[2*HD];
  __shared__ float red[HD];
  const int g = blockIdx.x, t = threadIdx.x;
  float s = pool[g*HD + t];
  float c = fmaxf(pcnt[g], 1.0f);
  z[t] = s; z[HD + t] = s / c;
  __syncthreads();
  float acc = bm1[t];
  for (int i=0;i<2*HD;i++) acc = fmaf(z[i], Wm1[i*HD + t], acc);
  acc = fmaxf(acc, 0.f);
  red[t] = acc * Wm2[t];
  __syncthreads();
  for (int off=64; off>0; off>>=1){
    if (t < off) red[t] += red[t+off];
    __syncthreads();
  }
  if (t == 0) out[g] = red[0] + bm2[0];
}

extern "C" void kernel_launch(void* const* d_in, const int* in_sizes, int n_in,
                              void* d_out, int out_size, void* d_ws, size_t ws_size,
                              hipStream_t stream){
  const float* x   = (const float*)d_in[0];
  const int*  ei   = (const int*)d_in[1];
  const int*  batch= (const int*)d_in[2];
  const float* W1  = (const float*)d_in[3];
  const float* b1  = (const float*)d_in[4];
  const float* W2  = (const float*)d_in[5];
  const float* b2  = (const float*)d_in[6];
  const float* W3  = (const float*)d_in[7];
  const float* b3  = (const float*)d_in[8];
  const float* g1  = (const float*)d_in[9];
  const float* be1 = (const float*)d_in[10];
  const float* g2  = (const float*)d_in[11];
  const float* be2 = (const float*)d_in[12];
  const float* g3  = (const float*)d_in[13];
  const float* be3 = (const float*)d_in[14];
  const float* Wm1 = (const float*)d_in[15];
  const float* bm1 = (const float*)d_in[16];
  const float* Wm2 = (const float*)d_in[17];
  const float* bm2 = (const float*)d_in[18];
  float* out = (float*)d_out;
  (void)in_sizes; (void)n_in; (void)out_size; (void)ws_size;

  // ---- workspace bump allocator (zeroed region first) ----
  char* p = (char*)d_ws;
  auto alloc = [&](size_t bytes)->void*{
    void* r = (void*)p;
    p += (bytes + 511) & ~(size_t)511;
    return r;
  };
  int*   deg    = (int*)  alloc(NN*sizeof(int));       // zeroed
  int*   cursor = (int*)  alloc(NN*sizeof(int));       // zeroed
  float* bns    = (float*)alloc(3*2*HD*sizeof(float)); // zeroed
  float* pool   = (float*)alloc(GG*HD*sizeof(float));  // zeroed
  float* pcnt   = (float*)alloc(GG*sizeof(float));     // zeroed
  size_t zbytes = (size_t)(p - (char*)d_ws);
  int*   offs   = (int*)  alloc((NN+1)*sizeof(int));
  int*   bsum   = (int*)  alloc(512*sizeof(int));
  float* dinv   = (float*)alloc(NN*sizeof(float));
  float* scale  = (float*)alloc(3*HD*sizeof(float));
  float* shift  = (float*)alloc(3*HD*sizeof(float));
  int2*  csr    = (int2*) alloc(((size_t)EE+8)*sizeof(int2)); // +8: pipeline pad
  ushort_t* hb  = (ushort_t*)alloc((size_t)NN*HD*sizeof(ushort_t)); // bf16 h
  float* agg    = (float*)alloc((size_t)NN*HD*sizeof(float));
  float* hres   = (float*)alloc((size_t)NN*HD*sizeof(float));

  hipMemsetAsync(d_ws, 0, zbytes, stream);

  // ---- CSR build ----
  k_hist   <<<(EE+255)/256, 256, 0, stream>>>(ei, deg);
  k_dinv   <<<NB, 256, 0, stream>>>(deg, dinv);
  k_scanA  <<<NB, 256, 0, stream>>>(deg, offs, bsum);
  k_scanB  <<<1, 512, 0, stream>>>(bsum);
  k_scanC  <<<NB, 256, 0, stream>>>(offs, bsum);
  k_scatter<<<(EE+255)/256, 256, 0, stream>>>(ei, offs, cursor, dinv, csr);

  const int GB = (NN+63)/64;
  // ---- layer 1 ----
  k_rowgemm<0><<<GB, 256, 0, stream>>>(x,   nullptr, W1, nullptr,    nullptr,    hb, nullptr);
  k_agg       <<<2048, 256, 0, stream>>>(hb, csr, offs, dinv, b1, agg, bns);
  k_bnfin     <<<1, 128, 0, stream>>>(bns,        g1, be1, scale,      shift);
  // ---- layer 2 ----
  k_rowgemm<1><<<GB, 256, 0, stream>>>(agg, nullptr, W2, scale,      shift,      hb, hres);
  k_agg       <<<2048, 256, 0, stream>>>(hb, csr, offs, dinv, b2, agg, bns + 2*HD);
  k_bnfin     <<<1, 128, 0, stream>>>(bns + 2*HD, g2, be2, scale+HD,   shift+HD);
  // ---- layer 3 ----
  k_rowgemm<2><<<GB, 256, 0, stream>>>(agg, hres,    W3, scale+HD,   shift+HD,   hb, hres);
  k_agg       <<<2048, 256, 0, stream>>>(hb, csr, offs, dinv, b3, agg, bns + 4*HD);
  k_bnfin     <<<1, 128, 0, stream>>>(bns + 4*HD, g3, be3, scale+2*HD, shift+2*HD);

  // ---- pooling + MLP ----
  k_pool<<<(NN+127)/128, 128, 0, stream>>>(agg, scale+2*HD, shift+2*HD, hres, batch, pool, pcnt);
  k_mlp <<<GG, 128, 0, stream>>>(pool, pcnt, Wm1, bm1, Wm2, bm2, out);
}